// Round 2
// baseline (5313.199 us; speedup 1.0000x reference)
//
#include <hip/hip_runtime.h>
#include <stdint.h>

#define DD 256
#define NEDGE 300000
#define NNODE 100000
#define NLAY 9
#define LN_EPS 1e-5f

typedef __attribute__((ext_vector_type(8))) short bf16x8;
typedef __attribute__((ext_vector_type(4))) short s16x4;
typedef __attribute__((ext_vector_type(4))) float f32x4;
typedef __attribute__((ext_vector_type(4))) int i32x4;

static __device__ __forceinline__ short f2bf(float f) {
  union { float f; uint32_t u; } v; v.f = f;
  uint32_t r = (v.u + 0x7FFFu + ((v.u >> 16) & 1u)) >> 16;
  return (short)(uint16_t)r;
}
static __device__ __forceinline__ float bf2f(short s) {
  union { uint32_t u; float f; } v; v.u = ((uint32_t)(uint16_t)s) << 16;
  return v.f;
}

static __device__ __forceinline__ void gld16(const void* g, void* l) {
  __builtin_amdgcn_global_load_lds((const __attribute__((address_space(1))) void*)g,
                                   (__attribute__((address_space(3))) void*)l, 16, 0, 0);
}

// ---------------------------------------------------------------------------
// Fused MLP: out = LN(relu(A @ W1^T + b1) @ W2^T + b2) * g + b  [+ resid]
// 256 thr = 4 waves, wave = 64 rows x 64 cols (1M x 4N). BM=64, K-step 32.
// W staged via global_load_lds into double-buffered LDS; 1 barrier / K-step.
// ---------------------------------------------------------------------------
template<bool A_BF16, bool NODE>
__global__ __launch_bounds__(256, 2) void mlp_kernel(
    const void* __restrict__ Ain, const int* __restrict__ rowmap,
    const short* __restrict__ W1, const short* __restrict__ W2,
    const float* __restrict__ B1, const float* __restrict__ B2,
    const float* __restrict__ LG, const float* __restrict__ LB,
    short* __restrict__ OutB, float* __restrict__ OutF,
    const float* __restrict__ Resid, short* __restrict__ XbOut, int M) {
  extern __shared__ char smem[];
  short* hidden = (short*)(smem + 32768);  // [64][256] bf16, granule-swizzled
  const int tid = threadIdx.x;
  const int lane = tid & 63;
  const int wv = tid >> 6;       // N-chunk of 64 cols
  const int l15 = lane & 15, lq = lane >> 4;
  const int r0 = blockIdx.x * 64;
  const int cbase = wv * 64;

  f32x4 acc[4][4];
#pragma unroll
  for (int mi = 0; mi < 4; ++mi)
#pragma unroll
    for (int ni = 0; ni < 4; ++ni) acc[mi][ni] = (f32x4){0.f, 0.f, 0.f, 0.f};

  const short* abf[4];
  const float* af[4];
#pragma unroll
  for (int mi = 0; mi < 4; ++mi) {
    const int ar = min(r0 + mi * 16 + l15, M - 1);
    if (A_BF16) abf[mi] = (const short*)Ain + (size_t)ar * DD;
    else        af[mi]  = (const float*)Ain + (size_t)(rowmap ? rowmap[ar] : ar) * DD;
  }

  auto stageW = [&](const short* W, int kk, int b) {
    const short* g = W + (size_t)(cbase + lane) * DD + kk * 32;
    char* base = smem + b * 16384 + cbase * 16;
#pragma unroll
    for (int i = 0; i < 4; ++i) gld16(g + i * 8, base + i * 4096);
  };

  // ------------------------- GEMM1: h = relu(A @ W1^T + b1) ----------------
  stageW(W1, 0, 0);
  __syncthreads();
#pragma unroll
  for (int kk = 0; kk < 8; ++kk) {
    if (kk < 7) stageW(W1, kk + 1, (kk + 1) & 1);
    bf16x8 a[4];
#pragma unroll
    for (int mi = 0; mi < 4; ++mi) {
      if (A_BF16) {
        a[mi] = *(const bf16x8*)(abf[mi] + kk * 32 + lq * 8);
      } else {
        const f32x4 u0 = *(const f32x4*)(af[mi] + kk * 32 + lq * 8);
        const f32x4 u1 = *(const f32x4*)(af[mi] + kk * 32 + lq * 8 + 4);
#pragma unroll
        for (int j = 0; j < 4; ++j) { a[mi][j] = f2bf(u0[j]); a[mi][j + 4] = f2bf(u1[j]); }
      }
    }
    const short* wb = (const short*)(smem + (kk & 1) * 16384);
#pragma unroll
    for (int ni = 0; ni < 4; ++ni) {
      const bf16x8 b = *(const bf16x8*)(wb + (lq * 256 + cbase + ni * 16 + l15) * 8);
#pragma unroll
      for (int mi = 0; mi < 4; ++mi)
        acc[mi][ni] = __builtin_amdgcn_mfma_f32_16x16x32_bf16(a[mi], b, acc[mi][ni], 0, 0, 0);
    }
    __syncthreads();
  }
  // epilogue 1: bias + relu -> hidden (granule-swizzled bf16)
#pragma unroll
  for (int ni = 0; ni < 4; ++ni) {
    const int c = cbase + ni * 16 + l15;
    const float bb = B1[c];
#pragma unroll
    for (int mi = 0; mi < 4; ++mi)
#pragma unroll
      for (int i = 0; i < 4; ++i) {
        const int row = mi * 16 + lq * 4 + i;
        hidden[row * DD + ((((c >> 3) ^ (row & 7))) << 3) + (c & 7)] =
            f2bf(fmaxf(acc[mi][ni][i] + bb, 0.f));
        acc[mi][ni][i] = 0.f;
      }
  }
  stageW(W2, 0, 0);
  __syncthreads();
  // ------------------------- GEMM2: y = h @ W2^T ---------------------------
#pragma unroll
  for (int kk = 0; kk < 8; ++kk) {
    if (kk < 7) stageW(W2, kk + 1, (kk + 1) & 1);
    bf16x8 a[4];
#pragma unroll
    for (int mi = 0; mi < 4; ++mi) {
      const int hr = mi * 16 + l15;
      a[mi] = *(const bf16x8*)(hidden + hr * DD + (((kk * 4 + lq) ^ (hr & 7)) << 3));
    }
    const short* wb = (const short*)(smem + (kk & 1) * 16384);
#pragma unroll
    for (int ni = 0; ni < 4; ++ni) {
      const bf16x8 b = *(const bf16x8*)(wb + (lq * 256 + cbase + ni * 16 + l15) * 8);
#pragma unroll
      for (int mi = 0; mi < 4; ++mi)
        acc[mi][ni] = __builtin_amdgcn_mfma_f32_16x16x32_bf16(a[mi], b, acc[mi][ni], 0, 0, 0);
    }
    __syncthreads();
  }
  // epilogue 2: bias + LayerNorm
  float b2v[4], gv[4], bv[4];
#pragma unroll
  for (int ni = 0; ni < 4; ++ni) {
    const int c = cbase + ni * 16 + l15;
    b2v[ni] = B2[c]; gv[ni] = LG[c]; bv[ni] = LB[c];
  }
  float mean_[4][4], inv_[4][4];
  float* redbuf = (float*)smem;  // wbuf region free now
#pragma unroll
  for (int mi = 0; mi < 4; ++mi)
#pragma unroll
    for (int i = 0; i < 4; ++i) {
      float s1 = 0.f, s2 = 0.f;
#pragma unroll
      for (int ni = 0; ni < 4; ++ni) {
        const float v = acc[mi][ni][i] + b2v[ni];
        s1 += v; s2 += v * v;
      }
#pragma unroll
      for (int off = 1; off < 16; off <<= 1) {
        s1 += __shfl_xor(s1, off);
        s2 += __shfl_xor(s2, off);
      }
      mean_[mi][i] = s1; inv_[mi][i] = s2;  // per-wave 64-col partials
    }
  if (l15 == 0) {
#pragma unroll
    for (int mi = 0; mi < 4; ++mi)
#pragma unroll
      for (int i = 0; i < 4; ++i) {
        const int row = mi * 16 + lq * 4 + i;
        redbuf[(row * 4 + wv) * 2 + 0] = mean_[mi][i];
        redbuf[(row * 4 + wv) * 2 + 1] = inv_[mi][i];
      }
  }
  __syncthreads();
#pragma unroll
  for (int mi = 0; mi < 4; ++mi)
#pragma unroll
    for (int i = 0; i < 4; ++i) {
      const int row = mi * 16 + lq * 4 + i;
      float t1 = 0.f, t2 = 0.f;
#pragma unroll
      for (int w = 0; w < 4; ++w) {
        t1 += redbuf[(row * 4 + w) * 2 + 0];
        t2 += redbuf[(row * 4 + w) * 2 + 1];
      }
      const float mean = t1 * (1.f / 256.f);
      const float var = t2 * (1.f / 256.f) - mean * mean;
      mean_[mi][i] = mean;
      inv_[mi][i] = rsqrtf(var + LN_EPS);
    }
  __syncthreads();  // redbuf consumed; smem reusable for output transpose

  if (NODE) {
    float* ob = (float*)smem;  // [64][256] f32, granule-swizzled (64KB)
#pragma unroll
    for (int ni = 0; ni < 4; ++ni) {
      const int c = cbase + ni * 16 + l15;
      const int g = c >> 2;
#pragma unroll
      for (int mi = 0; mi < 4; ++mi)
#pragma unroll
        for (int i = 0; i < 4; ++i) {
          const int row = mi * 16 + lq * 4 + i;
          const float y = (acc[mi][ni][i] + b2v[ni] - mean_[mi][i]) * inv_[mi][i] * gv[ni] + bv[ni];
          ob[row * DD + ((g ^ (row & 7)) << 2) + (c & 3)] = y;
        }
    }
    __syncthreads();
#pragma unroll
    for (int j = 0; j < 16; ++j) {
      const int gg = tid + 256 * j;
      const int row = gg >> 6, Lg = gg & 63;
      const int grow = r0 + row;
      if (grow < M) {
        f32x4 v = *(const f32x4*)(ob + row * DD + ((Lg ^ (row & 7)) << 2));
        const f32x4 xr = *(const f32x4*)(Resid + (size_t)grow * DD + Lg * 4);
        v = v + xr;
        *(f32x4*)(OutF + (size_t)grow * DD + Lg * 4) = v;
        s16x4 o; o.x = f2bf(v.x); o.y = f2bf(v.y); o.z = f2bf(v.z); o.w = f2bf(v.w);
        *(s16x4*)(XbOut + (size_t)grow * DD + Lg * 4) = o;
      }
    }
  } else {
    short* ob = hidden;  // reuse hidden region, same swizzle
#pragma unroll
    for (int ni = 0; ni < 4; ++ni) {
      const int c = cbase + ni * 16 + l15;
#pragma unroll
      for (int mi = 0; mi < 4; ++mi)
#pragma unroll
        for (int i = 0; i < 4; ++i) {
          const int row = mi * 16 + lq * 4 + i;
          const float y = (acc[mi][ni][i] + b2v[ni] - mean_[mi][i]) * inv_[mi][i] * gv[ni] + bv[ni];
          ob[row * DD + (((c >> 3) ^ (row & 7)) << 3) + (c & 7)] = f2bf(y);
        }
    }
    __syncthreads();
#pragma unroll
    for (int j = 0; j < 8; ++j) {
      const int gg = tid + 256 * j;
      const int row = gg >> 5, Lg = gg & 31;
      const int grow = r0 + row;
      if (grow < M) {
        const i32x4 v = *(const i32x4*)(ob + row * DD + ((Lg ^ (row & 7)) << 3));
        *(i32x4*)(OutB + (size_t)grow * DD + Lg * 8) = v;
      }
    }
  }
}

// ----------------------- aggregation: wave per node, CSR-sorted efeat ------
__global__ __launch_bounds__(256) void aggregate_kernel(
    const short* __restrict__ xb, const short* __restrict__ efs,
    const int* __restrict__ offs, const int* __restrict__ ssrc,
    short* __restrict__ aggr) {
  const int w = (blockIdx.x * blockDim.x + threadIdx.x) >> 6;
  if (w >= NNODE) return;
  const int lane = threadIdx.x & 63;
  const int beg = offs[w], end = offs[w + 1];
  float s0 = 0.f, s1 = 0.f, s2 = 0.f, s3 = 0.f;
  for (int p = beg; p < end; ++p) {
    const s16x4 ev = *(const s16x4*)(efs + (size_t)p * DD + lane * 4);
    const s16x4 xv = *(const s16x4*)(xb + (size_t)ssrc[p] * DD + lane * 4);
    s0 += bf2f(ev.x) + bf2f(xv.x);
    s1 += bf2f(ev.y) + bf2f(xv.y);
    s2 += bf2f(ev.z) + bf2f(xv.z);
    s3 += bf2f(ev.w) + bf2f(xv.w);
  }
  s16x4 o; o.x = f2bf(s0); o.y = f2bf(s1); o.z = f2bf(s2); o.w = f2bf(s3);
  *(s16x4*)(aggr + (size_t)w * DD + lane * 4) = o;
}

__global__ void count_kernel(const int* __restrict__ tgt, int* __restrict__ deg) {
  const int e = blockIdx.x * 256 + threadIdx.x;
  if (e < NEDGE) atomicAdd(&deg[tgt[e]], 1);
}

__global__ __launch_bounds__(1024) void scan_kernel(
    const int* __restrict__ deg, int* __restrict__ offs, int* __restrict__ cur) {
  __shared__ int part[1024];
  const int t = threadIdx.x;
  const int CH = 98;  // 1024*98 >= 100000
  const int base = t * CH;
  int s = 0;
  for (int i = 0; i < CH; ++i) {
    const int idx = base + i;
    if (idx < NNODE) s += deg[idx];
  }
  part[t] = s;
  __syncthreads();
  for (int off = 1; off < 1024; off <<= 1) {
    const int v = (t >= off) ? part[t - off] : 0;
    __syncthreads();
    part[t] += v;
    __syncthreads();
  }
  int run = (t > 0) ? part[t - 1] : 0;  // exclusive prefix
  for (int i = 0; i < CH; ++i) {
    const int idx = base + i;
    if (idx < NNODE) {
      offs[idx] = run;
      cur[idx] = run;
      run += deg[idx];
    }
  }
  if (t == 1023) offs[NNODE] = part[1023];
}

__global__ void fill_kernel(const int* __restrict__ src, const int* __restrict__ tgt,
                            int* cur, int* seid, int* ssrc) {
  const int e = blockIdx.x * 256 + threadIdx.x;
  if (e < NEDGE) {
    const int t = tgt[e];
    const int p = atomicAdd(&cur[t], 1);
    seid[p] = e;
    ssrc[p] = src[e];
  }
}

__global__ void cvt4_kernel(const float* __restrict__ src, short* __restrict__ dst, int n4) {
  for (int i = blockIdx.x * blockDim.x + threadIdx.x; i < n4; i += gridDim.x * blockDim.x) {
    const f32x4 v = ((const f32x4*)src)[i];
    s16x4 o;
    o.x = f2bf(v.x); o.y = f2bf(v.y); o.z = f2bf(v.z); o.w = f2bf(v.w);
    ((s16x4*)dst)[i] = o;
  }
}

// gather rows by perm and convert f32 -> bf16 (wave per row)
__global__ __launch_bounds__(256) void gather_cvt_kernel(
    const float* __restrict__ src, const int* __restrict__ perm,
    short* __restrict__ dst, int n) {
  const int w = (blockIdx.x * blockDim.x + threadIdx.x) >> 6;
  if (w >= n) return;
  const int lane = threadIdx.x & 63;
  const f32x4 v = *(const f32x4*)(src + (size_t)perm[w] * DD + lane * 4);
  s16x4 o; o.x = f2bf(v.x); o.y = f2bf(v.y); o.z = f2bf(v.z); o.w = f2bf(v.w);
  *(s16x4*)(dst + (size_t)w * DD + lane * 4) = o;
}

// ---------------------------------------------------------------------------
extern "C" void kernel_launch(void* const* d_in, const int* in_sizes, int n_in,
                              void* d_out, int out_size, void* d_ws, size_t ws_size,
                              hipStream_t stream) {
  const float* x_in = (const float*)d_in[0];
  const float* ea_f = (const float*)d_in[1];
  const float* e1w = (const float*)d_in[2];
  const float* e1b = (const float*)d_in[3];
  const float* e2w = (const float*)d_in[4];
  const float* e2b = (const float*)d_in[5];
  const float* elg = (const float*)d_in[6];
  const float* elb = (const float*)d_in[7];
  const float* n1w = (const float*)d_in[8];
  const float* n1b = (const float*)d_in[9];
  const float* n2w = (const float*)d_in[10];
  const float* n2b = (const float*)d_in[11];
  const float* nlg = (const float*)d_in[12];
  const float* nlb = (const float*)d_in[13];
  const int* eidx = (const int*)d_in[14];
  float* x = (float*)d_out;

  char* p = (char*)d_ws;
  auto take = [&](size_t bytes) {
    char* r = p;
    p += (bytes + 255) & ~(size_t)255;
    return r;
  };
  short* efeat = (short*)take((size_t)NEDGE * DD * 2);  // sorted-order edge MLP out
  short* aggr = (short*)take((size_t)NNODE * DD * 2);
  short* xb = (short*)take((size_t)NNODE * DD * 2);     // bf16 mirror of x
  short* we1 = (short*)take((size_t)NLAY * DD * DD * 2);
  short* we2 = (short*)take((size_t)NLAY * DD * DD * 2);
  short* wn1 = (short*)take((size_t)NLAY * DD * DD * 2);
  short* wn2 = (short*)take((size_t)NLAY * DD * DD * 2);
  int* deg = (int*)take((size_t)NNODE * 4);
  int* offs = (int*)take((size_t)(NNODE + 1) * 4);
  int* cur = (int*)take((size_t)NNODE * 4);
  int* seid = (int*)take((size_t)NEDGE * 4);
  int* ssrc = (int*)take((size_t)NEDGE * 4);
  short* eab = (short*)take((size_t)NEDGE * DD * 2);    // sorted bf16 edge_attr
  const bool use_eab = ((size_t)(p - (char*)d_ws) <= ws_size);

  hipMemcpyAsync(x, x_in, (size_t)NNODE * DD * 4, hipMemcpyDeviceToDevice, stream);

  const int wn4 = NLAY * DD * DD / 4;
  cvt4_kernel<<<576, 256, 0, stream>>>(e1w, we1, wn4);
  cvt4_kernel<<<576, 256, 0, stream>>>(e2w, we2, wn4);
  cvt4_kernel<<<576, 256, 0, stream>>>(n1w, wn1, wn4);
  cvt4_kernel<<<576, 256, 0, stream>>>(n2w, wn2, wn4);
  cvt4_kernel<<<2048, 256, 0, stream>>>(x_in, xb, NNODE * DD / 4);

  hipMemsetAsync(deg, 0, (size_t)NNODE * 4, stream);
  count_kernel<<<(NEDGE + 255) / 256, 256, 0, stream>>>(eidx + NEDGE, deg);
  scan_kernel<<<1, 1024, 0, stream>>>(deg, offs, cur);
  fill_kernel<<<(NEDGE + 255) / 256, 256, 0, stream>>>(eidx, eidx + NEDGE, cur, seid, ssrc);
  if (use_eab)
    gather_cvt_kernel<<<NEDGE / 4, 256, 0, stream>>>(ea_f, seid, eab, NEDGE);

  const int egrid = (NEDGE + 63) / 64;
  const int ngrid = (NNODE + 63) / 64;
  for (int l = 0; l < NLAY; ++l) {
    if (use_eab) {
      mlp_kernel<true, false><<<egrid, 256, 65536, stream>>>(
          eab, nullptr, we1 + l * DD * DD, we2 + l * DD * DD, e1b + l * DD,
          e2b + l * DD, elg + l * DD, elb + l * DD, efeat, nullptr, nullptr,
          nullptr, NEDGE);
    } else {
      mlp_kernel<false, false><<<egrid, 256, 65536, stream>>>(
          ea_f, seid, we1 + l * DD * DD, we2 + l * DD * DD, e1b + l * DD,
          e2b + l * DD, elg + l * DD, elb + l * DD, efeat, nullptr, nullptr,
          nullptr, NEDGE);
    }
    aggregate_kernel<<<(NNODE * 64 + 255) / 256, 256, 0, stream>>>(xb, efeat, offs, ssrc, aggr);
    mlp_kernel<true, true><<<ngrid, 256, 65536, stream>>>(
        aggr, nullptr, wn1 + l * DD * DD, wn2 + l * DD * DD, n1b + l * DD,
        n2b + l * DD, nlg + l * DD, nlb + l * DD, nullptr, x, x, xb, NNODE);
  }
  (void)in_sizes; (void)n_in; (void)out_size; (void)ws_size;
}